// Round 13
// baseline (156.769 us; speedup 1.0000x reference)
//
#include <hip/hip_runtime.h>

#define FD  128
#define NN  2048

// workspace layout (float elements) — identical to the 156us R4 build
#define OFF_X     0            // x[n][f]            2048*128
#define OFF_PROJ  262144       // proj[n][r*128+o]   2048*256
#define OFF_QS    786432       // qs[r][n]           2*2048
#define OFF_KS    790528       // ks[r][n]           2*2048
#define OFF_SUMS  794624       // l*2048 + slot*256 + {0:sum,128:sumsq}, 8 slots
#define OFF_LWT   800768       // l*32768 + c*128 + o
#define OFF_M2    899072       // m2[n][f]

// XCD-affine swizzle for 512 blocks: bid&7 = XCD; graph = XCD pair; 128
// slots x 4 rows per graph. Producer/consumer kernels share the mapping so
// proj/x/m2 for a graph stay in the same XCD pair's L2.
__device__ __forceinline__ int swizzle_n0(int bid) {
    int g    = (bid & 7) >> 1;                 // graph 0..3
    int slot = ((bid >> 3) << 1) | (bid & 1);  // 0..127
    return g*512 + slot*4;                     // first of 4 rows
}

// proj GEMM for 4 rows (xs in LDS), K split across two thread-halves,
// fused qs/ks scalars. 512 threads.
__device__ __forceinline__ void proj_qsks4(
    const float* __restrict__ W, const float* __restrict__ qv,
    const float* __restrict__ kv, float* __restrict__ ws,
    int l, int n0, int t, const float (*xs)[FD],
    float (*redp)[256], float* red)
{
    int kh = t >> 8, tp = t & 255;
    int rsel = tp >> 7, o = tp & 127;
    const float* Wl = W + ((size_t)(l*2 + rsel)*FD)*FD + o;
    float acc[4];
#pragma unroll
    for (int r = 0; r < 4; r++) acc[r] = 0.f;
    int kbase = kh * 64;
#pragma unroll
    for (int kk = 0; kk < 64; kk += 4) {
        int k4 = kbase + kk;
        float w0 = Wl[(k4+0)*FD], w1 = Wl[(k4+1)*FD];
        float w2 = Wl[(k4+2)*FD], w3 = Wl[(k4+3)*FD];
#pragma unroll
        for (int r = 0; r < 4; r++) {
            float4 xq = *(const float4*)&xs[r][k4];
            acc[r] += xq.x*w0 + xq.y*w1 + xq.z*w2 + xq.w*w3;
        }
    }
    if (kh == 1) {
#pragma unroll
        for (int r = 0; r < 4; r++) redp[r][tp] = acc[r];
    }
    __syncthreads();
    if (t < 256) {
#pragma unroll
        for (int r = 0; r < 4; r++) acc[r] += redp[r][tp];
#pragma unroll
        for (int r = 0; r < 4; r++)
            ws[OFF_PROJ + (size_t)(n0 + r)*256 + tp] = acc[r];

        float qq = qv[l*FD + o], kq = kv[l*FD + o];
        int lane = t & 63, w = t >> 6;    // w in 0..3
#pragma unroll
        for (int r = 0; r < 4; r++) {
            float vq = acc[r]*qq, vk = acc[r]*kq;
            for (int off = 32; off; off >>= 1) {
                vq += __shfl_xor(vq, off, 64);
                vk += __shfl_xor(vk, off, 64);
            }
            if (lane == 0) { red[w*8 + r*2] = vq; red[w*8 + r*2 + 1] = vk; }
        }
    }
    __syncthreads();
    if (t < 16) {
        int r = t & 3, rs = (t >> 2) & 1, wh = t >> 3;
        float v = red[(rs*2)*8 + r*2 + wh] + red[(rs*2 + 1)*8 + r*2 + wh];
        if (wh == 0) ws[OFF_QS + rs*NN + n0 + r] = v;
        else         ws[OFF_KS + rs*NN + n0 + r] = v;
    }
}

// ---------------- k_pre: input transpose + proj(0) + linWT(all l) + zero sums
__global__ __launch_bounds__(512, 4) void k_pre(
    const float* __restrict__ d0, const float* __restrict__ d1,
    const float* __restrict__ W,  const float* __restrict__ qv,
    const float* __restrict__ kv, const float* __restrict__ linW,
    float* __restrict__ ws)
{
    int bid = blockIdx.x, t = threadIdx.x;
    if (bid >= 512) {
        if (bid < 536) {               // linWT[l][c][o] = lin_W[l][o][c]
            int vb = bid - 512;        // 0..23
#pragma unroll
            for (int i = 0; i < 8; i++) {
                int e = vb*4096 + i*512 + t;   // 0..98303
                int l = e >> 15, rem = e & 32767;
                int o = rem >> 8, c = rem & 255;
                ws[OFF_LWT + l*32768 + c*FD + o] = linW[e];
            }
        } else {
            for (int i = t; i < 6144; i += 512) ws[OFF_SUMS + i] = 0.f;
        }
        return;
    }
    __shared__ __attribute__((aligned(16))) float xs[4][FD];
    __shared__ float redp[4][256];
    __shared__ float red[32];
    int n0 = swizzle_n0(bid);
    {
        int row = t >> 7, f = t & 127;
        int n = n0 + row, gg = n >> 9, ii = n & 511;
        float v = (ii < 256) ? d0[gg*32768 + f*256 + ii]
                             : d1[gg*32768 + f*256 + (ii - 256)];
        xs[row][f] = v;
        ws[OFF_X + (size_t)n*FD + f] = v;
    }
    __syncthreads();
    proj_qsks4(W, qv, kv, ws, 0, n0, t, xs, redp, red);
}

// ---------------- k_bp: BN(l-1) apply + residual + proj(l). 512 blocks x 4 rows.
// x/m2 operands prefetched at entry (independent of the SUMS-derived scale).
__global__ __launch_bounds__(512, 4) void k_bp(
    const float* __restrict__ W,     const float* __restrict__ qv,
    const float* __restrict__ kv,    const float* __restrict__ gamma,
    const float* __restrict__ beta,  float* __restrict__ ws, int l)
{
    __shared__ float scale[FD], shift[FD];
    __shared__ __attribute__((aligned(16))) float xs[4][FD];
    __shared__ float redp[4][256];
    __shared__ float red[32];
    int bid = blockIdx.x, t = threadIdx.x;
    int lp = l - 1;
    int n0 = swizzle_n0(bid);
    int row = t >> 7, f = t & 127;
    size_t e = (size_t)(n0 + row)*FD + f;
    float xm  = ws[OFF_X + e];      // early issue: hides under SUMS phase
    float m2v = ws[OFF_M2 + e];
    if (t < 128) {
        float s0 = 0.f, s1 = 0.f;
#pragma unroll
        for (int sl = 0; sl < 8; sl++) {
            s0 += ws[OFF_SUMS + lp*2048 + sl*256 + t];
            s1 += ws[OFF_SUMS + lp*2048 + sl*256 + 128 + t];
        }
        float mu  = s0 * (1.f/2048.f);
        float var = s1 * (1.f/2048.f) - mu*mu;
        float rs  = rsqrtf(var + 1e-5f);
        float gm  = gamma[lp*FD + t], bt = beta[lp*FD + t];
        scale[t] = gm * rs;
        shift[t] = bt - mu * gm * rs;
    }
    __syncthreads();
    {
        float xv = xm + m2v*scale[f] + shift[f];
        xs[row][f] = xv;
        ws[OFF_X + e] = xv;
    }
    __syncthreads();
    proj_qsks4(W, qv, kv, ws, l, n0, t, xs, redp, red);
}

// ---------------- k_attn: dense attention + m1 + m2 GEMM + BN partials
// 512 blocks x 512 threads, 4 dst/block -> 2 blocks/CU (16 waves/CU).
// R10's measured-best structure: 8 barriers, 3-deep pipelines, first 2 proj
// groups + epilogue operands issued at kernel entry.
__global__ __launch_bounds__(512, 4) void k_attn(
    const float* __restrict__ convb, const float* __restrict__ linb,
    float* __restrict__ ws, int l)
{
    __shared__ __attribute__((aligned(16))) float att[4*512];    // 8K
    __shared__ __attribute__((aligned(16))) float redB[8*4*128]; // 16K
    __shared__ __attribute__((aligned(16))) float cat[4*256];    // 4K
    __shared__ float sml[4][2], sls[4][2];
    __shared__ float r1[FD], r2[FD];

    int bid = blockIdx.x, t = threadIdx.x;
    int dstbase = swizzle_n0(bid);
    int g = dstbase >> 9, dloc0 = dstbase & 511;
    int Gd = (dloc0 >= 256) ? 1 : 0;

    // --- early issue: phase-B first 2 proj groups + epilogue operands.
    int f4 = t & 31, sq = t >> 5;
    int ts = (sq < 8) ? Gd : 1 - Gd;
    const float* P = ws + OFF_PROJ + (size_t)(g*512)*256 + ts*128 + f4*4;
    int s0 = sq * 32;
    float4 buf0[4], buf1[4], buf2[4];
#pragma unroll
    for (int u = 0; u < 4; u++) buf0[u] = *(const float4*)&P[(size_t)(s0+u)*256];
#pragma unroll
    for (int u = 0; u < 4; u++) buf1[u] = *(const float4*)&P[(size_t)(s0+4+u)*256];
    float xpre = ws[OFF_X + (size_t)(dstbase + (t >> 7))*FD + (t & 127)];
    float cb   = convb[l*FD + (t & 127)];
    float lb   = linb[l*FD + (t & 127)];

    // stats: 8 waves, 2 per dst row (half src-range each), merged via LDS
    {
        int w = t >> 6, p = t & 63;
        int d = w >> 1, h = w & 1;
        int dloc = dloc0 + d;
        float q0 = ws[OFF_QS + dstbase + d];
        float q1 = ws[OFF_QS + NN + dstbase + d];
        float sc[4];
#pragma unroll
        for (int j = 0; j < 4; j++) {
            int s = h*256 + p + j*64;
            int tss = (s < 256) ? Gd : 1 - Gd;
            float a = (tss ? q1 : q0) + ws[OFF_KS + tss*NN + g*512 + s];
            a = a > 0.f ? a : 0.2f*a;
            sc[j] = (s == dloc) ? -1e30f : a;
        }
        float lm = fmaxf(fmaxf(sc[0], sc[1]), fmaxf(sc[2], sc[3]));
        for (int off = 32; off; off >>= 1) lm = fmaxf(lm, __shfl_xor(lm, off, 64));
        float ex[4], lsum = 0.f;
#pragma unroll
        for (int j = 0; j < 4; j++) { ex[j] = __expf(sc[j] - lm); lsum += ex[j]; }
        for (int off = 32; off; off >>= 1) lsum += __shfl_xor(lsum, off, 64);
#pragma unroll
        for (int j = 0; j < 4; j++) att[d*512 + h*256 + p + j*64] = ex[j];
        if (p == 0) { sml[d][h] = lm; sls[d][h] = lsum; }
    }
    __syncthreads();
    // normalize across the two halves (exact up to rounding) + zero r1/r2
    {
        int d = t >> 7, s4 = (t & 127) * 4;
        int h = (s4 >= 256) ? 1 : 0;
        float m0 = sml[d][0], m1 = sml[d][1];
        float M = fmaxf(m0, m1);
        float denom = sls[d][0]*__expf(m0 - M) + sls[d][1]*__expf(m1 - M) + 1e-16f;
        float fac = __expf(sml[d][h] - M) / denom;
        float4 a4 = *(float4*)&att[d*512 + s4];
        a4.x *= fac; a4.y *= fac; a4.z *= fac; a4.w *= fac;
        *(float4*)&att[d*512 + s4] = a4;
        if (t < 128) r1[t] = 0.f;
        else if (t < 256) r2[t - 128] = 0.f;
    }
    __syncthreads();

    // phase B: thread = (f4 -> 4 f's, sq -> 32-src chunk); 3-deep pipeline
    // (2 groups in flight ~256cy lead > ~225cy L2 latency).
    float acc[4][4];
#pragma unroll
    for (int d2 = 0; d2 < 4; d2++)
#pragma unroll
        for (int j = 0; j < 4; j++) acc[d2][j] = 0.f;
    {
#pragma unroll
        for (int ii = 0; ii < 8; ii++) {
            const float4* cur = (ii % 3 == 0) ? buf0 : (ii % 3 == 1) ? buf1 : buf2;
            float4* nxt = ((ii+2) % 3 == 0) ? buf0 : ((ii+2) % 3 == 1) ? buf1 : buf2;
            if (ii < 6) {
#pragma unroll
                for (int u = 0; u < 4; u++)
                    nxt[u] = *(const float4*)&P[(size_t)(s0 + (ii+2)*4 + u)*256];
            }
#pragma unroll
            for (int u = 0; u < 4; u++) {
                int s = s0 + ii*4 + u;
                float4 p4 = cur[u];
#pragma unroll
                for (int d2 = 0; d2 < 4; d2++) {
                    float b = att[d2*512 + s];
                    acc[d2][0] += b*p4.x; acc[d2][1] += b*p4.y;
                    acc[d2][2] += b*p4.z; acc[d2][3] += b*p4.w;
                }
            }
        }
    }
    // staged reduction 16 -> 8 partial chunks
    if (sq >= 8) {
#pragma unroll
        for (int d2 = 0; d2 < 4; d2++)
            *(float4*)&redB[((sq - 8)*4 + d2)*128 + f4*4] =
                make_float4(acc[d2][0], acc[d2][1], acc[d2][2], acc[d2][3]);
    }
    __syncthreads();
    if (sq < 8) {
#pragma unroll
        for (int d2 = 0; d2 < 4; d2++) {
            float4 p4 = *(const float4*)&redB[(sq*4 + d2)*128 + f4*4];
            *(float4*)&redB[(sq*4 + d2)*128 + f4*4] =
                make_float4(acc[d2][0]+p4.x, acc[d2][1]+p4.y, acc[d2][2]+p4.z, acc[d2][3]+p4.w);
        }
    }
    __syncthreads();

    // agg reduce (1 output/thread); m1 = relu(agg + conv_b); cat = [x | m1]
    {
        int d2 = t >> 7, f = t & 127;
        float agg = 0.f;
#pragma unroll
        for (int cc = 0; cc < 8; cc++) agg += redB[(cc*4 + d2)*128 + f];
        float m1v = fmaxf(agg + cb, 0.f);
        cat[d2*256 + FD + f] = m1v;
        cat[d2*256 + f] = xpre;
    }
    __syncthreads();

    // m2 GEMM: thread = (f4 -> 4 o's, sq -> 16-c chunk), 3-deep pipeline
#pragma unroll
    for (int d2 = 0; d2 < 4; d2++)
#pragma unroll
        for (int j = 0; j < 4; j++) acc[d2][j] = 0.f;
    {
        const float* lwt = ws + OFF_LWT + l*32768 + f4*4;
        int c0 = sq * 16;
#pragma unroll
        for (int u = 0; u < 4; u++) buf0[u] = *(const float4*)&lwt[(c0+u)*128];
#pragma unroll
        for (int u = 0; u < 4; u++) buf1[u] = *(const float4*)&lwt[(c0+4+u)*128];
#pragma unroll
        for (int ii = 0; ii < 4; ii++) {
            const float4* cur = (ii % 3 == 0) ? buf0 : (ii % 3 == 1) ? buf1 : buf2;
            float4* nxt = ((ii+2) % 3 == 0) ? buf0 : ((ii+2) % 3 == 1) ? buf1 : buf2;
            if (ii < 2) {
#pragma unroll
                for (int u = 0; u < 4; u++)
                    nxt[u] = *(const float4*)&lwt[(c0 + (ii+2)*4 + u)*128];
            }
#pragma unroll
            for (int u = 0; u < 4; u++) {
                int c = c0 + ii*4 + u;
                float4 w4 = cur[u];
#pragma unroll
                for (int d2 = 0; d2 < 4; d2++) {
                    float cv = cat[d2*256 + c];
                    acc[d2][0] += cv*w4.x; acc[d2][1] += cv*w4.y;
                    acc[d2][2] += cv*w4.z; acc[d2][3] += cv*w4.w;
                }
            }
        }
    }
    if (sq >= 8) {
#pragma unroll
        for (int d2 = 0; d2 < 4; d2++)
            *(float4*)&redB[((sq - 8)*4 + d2)*128 + f4*4] =
                make_float4(acc[d2][0], acc[d2][1], acc[d2][2], acc[d2][3]);
    }
    __syncthreads();
    if (sq < 8) {
#pragma unroll
        for (int d2 = 0; d2 < 4; d2++) {
            float4 p4 = *(const float4*)&redB[(sq*4 + d2)*128 + f4*4];
            *(float4*)&redB[(sq*4 + d2)*128 + f4*4] =
                make_float4(acc[d2][0]+p4.x, acc[d2][1]+p4.y, acc[d2][2]+p4.z, acc[d2][3]+p4.w);
        }
    }
    __syncthreads();

    // finalize m2 (1 output/thread), BN partials LDS -> global slots
    {
        int d2 = t >> 7, o = t & 127;
        float m2v = lb;
#pragma unroll
        for (int cc = 0; cc < 8; cc++) m2v += redB[(cc*4 + d2)*128 + o];
        ws[OFF_M2 + (size_t)(dstbase + d2)*FD + o] = m2v;
        atomicAdd(&r1[o], m2v);
        atomicAdd(&r2[o], m2v*m2v);
    }
    __syncthreads();
    if (t < 128) {
        int slot = bid & 7;   // XCD id -> atomics stay XCD-local
        atomicAdd(&ws[OFF_SUMS + l*2048 + slot*256 + t],       r1[t]);
        atomicAdd(&ws[OFF_SUMS + l*2048 + slot*256 + 128 + t], r2[t]);
    }
}

// ---------------- k_bnout: final BN + residual + output transpose
// x/m2 prefetched at entry (independent of the SUMS-derived scale).
__global__ __launch_bounds__(256) void k_bnout(
    const float* __restrict__ gamma, const float* __restrict__ beta,
    float* __restrict__ ws, float* __restrict__ out)
{
    __shared__ float scale[FD], shift[FD];
    int bid = blockIdx.x, t = threadIdx.x;
    float xm[2], mm[2];
#pragma unroll
    for (int i = 0; i < 2; i++) {      // early issue: hides under SUMS phase
        int idx = bid*512 + i*256 + t;
        xm[i] = ws[OFF_X + idx];
        mm[i] = ws[OFF_M2 + idx];
    }
    if (t < 128) {
        float s0 = 0.f, s1 = 0.f;
#pragma unroll
        for (int sl = 0; sl < 8; sl++) {
            s0 += ws[OFF_SUMS + 2*2048 + sl*256 + t];
            s1 += ws[OFF_SUMS + 2*2048 + sl*256 + 128 + t];
        }
        float mu  = s0 * (1.f/2048.f);
        float var = s1 * (1.f/2048.f) - mu*mu;
        float rs  = rsqrtf(var + 1e-5f);
        float gm  = gamma[2*FD + t], bt = beta[2*FD + t];
        scale[t] = gm * rs;
        shift[t] = bt - mu * gm * rs;
    }
    __syncthreads();
#pragma unroll
    for (int i = 0; i < 2; i++) {
        int idx = bid*512 + i*256 + t;
        int f = idx & 127, n = idx >> 7;
        float v = xm[i] + mm[i]*scale[f] + shift[f];
        int gg = n >> 9, ii = n & 511;
        int off = (ii < 256) ? (gg*32768 + f*256 + ii)
                             : (131072 + gg*32768 + f*256 + (ii - 256));
        out[off] = v;
    }
}

extern "C" void kernel_launch(void* const* d_in, const int* in_sizes, int n_in,
                              void* d_out, int out_size, void* d_ws, size_t ws_size,
                              hipStream_t stream) {
    (void)in_sizes; (void)n_in; (void)out_size; (void)ws_size;
    const float* desc0 = (const float*)d_in[0];
    const float* desc1 = (const float*)d_in[1];
    const float* W     = (const float*)d_in[2];
    const float* q     = (const float*)d_in[3];
    const float* kk    = (const float*)d_in[4];
    const float* convb = (const float*)d_in[5];
    const float* linW  = (const float*)d_in[6];
    const float* linb  = (const float*)d_in[7];
    const float* gamma = (const float*)d_in[8];
    const float* beta  = (const float*)d_in[9];
    float* ws  = (float*)d_ws;
    float* out = (float*)d_out;

    hipLaunchKernelGGL(k_pre,  dim3(537), dim3(512), 0, stream, desc0, desc1, W, q, kk, linW, ws);
    hipLaunchKernelGGL(k_attn, dim3(512), dim3(512), 0, stream, convb, linb, ws, 0);
    hipLaunchKernelGGL(k_bp,   dim3(512), dim3(512), 0, stream, W, q, kk, gamma, beta, ws, 1);
    hipLaunchKernelGGL(k_attn, dim3(512), dim3(512), 0, stream, convb, linb, ws, 1);
    hipLaunchKernelGGL(k_bp,   dim3(512), dim3(512), 0, stream, W, q, kk, gamma, beta, ws, 2);
    hipLaunchKernelGGL(k_attn, dim3(512), dim3(512), 0, stream, convb, linb, ws, 2);
    hipLaunchKernelGGL(k_bnout, dim3(512), dim3(256), 0, stream, gamma, beta, ws, out);
}

// Round 14
// 153.259 us; speedup vs baseline: 1.0229x; 1.0229x over previous
//
#include <hip/hip_runtime.h>

#define FD  128
#define NN  2048

// workspace layout (float elements) — identical to the 156us R4 build
#define OFF_X     0            // x[n][f]            2048*128
#define OFF_PROJ  262144       // proj[n][r*128+o]   2048*256
#define OFF_QS    786432       // qs[r][n]           2*2048
#define OFF_KS    790528       // ks[r][n]           2*2048
#define OFF_SUMS  794624       // l*2048 + slot*256 + {0:sum,128:sumsq}, 8 slots
#define OFF_LWT   800768       // l*32768 + c*128 + o
#define OFF_M2    899072       // m2[n][f]

// XCD-affine swizzle for 512 blocks: bid&7 = XCD; graph = XCD pair; 128
// slots x 4 rows per graph. Producer/consumer kernels share the mapping so
// proj/x/m2 for a graph stay in the same XCD pair's L2.
__device__ __forceinline__ int swizzle_n0(int bid) {
    int g    = (bid & 7) >> 1;                 // graph 0..3
    int slot = ((bid >> 3) << 1) | (bid & 1);  // 0..127
    return g*512 + slot*4;                     // first of 4 rows
}

// proj GEMM for 4 rows (xs in LDS), K split across two thread-halves,
// fused qs/ks scalars. 512 threads.
__device__ __forceinline__ void proj_qsks4(
    const float* __restrict__ W, const float* __restrict__ qv,
    const float* __restrict__ kv, float* __restrict__ ws,
    int l, int n0, int t, const float (*xs)[FD],
    float (*redp)[256], float* red)
{
    int kh = t >> 8, tp = t & 255;
    int rsel = tp >> 7, o = tp & 127;
    const float* Wl = W + ((size_t)(l*2 + rsel)*FD)*FD + o;
    float acc[4];
#pragma unroll
    for (int r = 0; r < 4; r++) acc[r] = 0.f;
    int kbase = kh * 64;
#pragma unroll
    for (int kk = 0; kk < 64; kk += 4) {
        int k4 = kbase + kk;
        float w0 = Wl[(k4+0)*FD], w1 = Wl[(k4+1)*FD];
        float w2 = Wl[(k4+2)*FD], w3 = Wl[(k4+3)*FD];
#pragma unroll
        for (int r = 0; r < 4; r++) {
            float4 xq = *(const float4*)&xs[r][k4];
            acc[r] += xq.x*w0 + xq.y*w1 + xq.z*w2 + xq.w*w3;
        }
    }
    if (kh == 1) {
#pragma unroll
        for (int r = 0; r < 4; r++) redp[r][tp] = acc[r];
    }
    __syncthreads();
    if (t < 256) {
#pragma unroll
        for (int r = 0; r < 4; r++) acc[r] += redp[r][tp];
#pragma unroll
        for (int r = 0; r < 4; r++)
            ws[OFF_PROJ + (size_t)(n0 + r)*256 + tp] = acc[r];

        float qq = qv[l*FD + o], kq = kv[l*FD + o];
        int lane = t & 63, w = t >> 6;    // w in 0..3
#pragma unroll
        for (int r = 0; r < 4; r++) {
            float vq = acc[r]*qq, vk = acc[r]*kq;
            for (int off = 32; off; off >>= 1) {
                vq += __shfl_xor(vq, off, 64);
                vk += __shfl_xor(vk, off, 64);
            }
            if (lane == 0) { red[w*8 + r*2] = vq; red[w*8 + r*2 + 1] = vk; }
        }
    }
    __syncthreads();
    if (t < 16) {
        int r = t & 3, rs = (t >> 2) & 1, wh = t >> 3;
        float v = red[(rs*2)*8 + r*2 + wh] + red[(rs*2 + 1)*8 + r*2 + wh];
        if (wh == 0) ws[OFF_QS + rs*NN + n0 + r] = v;
        else         ws[OFF_KS + rs*NN + n0 + r] = v;
    }
}

// ---------------- k_pre: input transpose + proj(0) + linWT(all l) + zero sums
__global__ __launch_bounds__(512, 4) void k_pre(
    const float* __restrict__ d0, const float* __restrict__ d1,
    const float* __restrict__ W,  const float* __restrict__ qv,
    const float* __restrict__ kv, const float* __restrict__ linW,
    float* __restrict__ ws)
{
    int bid = blockIdx.x, t = threadIdx.x;
    if (bid >= 512) {
        if (bid < 536) {               // linWT[l][c][o] = lin_W[l][o][c]
            int vb = bid - 512;        // 0..23
#pragma unroll
            for (int i = 0; i < 8; i++) {
                int e = vb*4096 + i*512 + t;   // 0..98303
                int l = e >> 15, rem = e & 32767;
                int o = rem >> 8, c = rem & 255;
                ws[OFF_LWT + l*32768 + c*FD + o] = linW[e];
            }
        } else {
            for (int i = t; i < 6144; i += 512) ws[OFF_SUMS + i] = 0.f;
        }
        return;
    }
    __shared__ __attribute__((aligned(16))) float xs[4][FD];
    __shared__ float redp[4][256];
    __shared__ float red[32];
    int n0 = swizzle_n0(bid);
    {
        int row = t >> 7, f = t & 127;
        int n = n0 + row, gg = n >> 9, ii = n & 511;
        float v = (ii < 256) ? d0[gg*32768 + f*256 + ii]
                             : d1[gg*32768 + f*256 + (ii - 256)];
        xs[row][f] = v;
        ws[OFF_X + (size_t)n*FD + f] = v;
    }
    __syncthreads();
    proj_qsks4(W, qv, kv, ws, 0, n0, t, xs, redp, red);
}

// ---------------- k_bp: BN(l-1) apply + residual + proj(l). 512 blocks x 4 rows.
__global__ __launch_bounds__(512, 4) void k_bp(
    const float* __restrict__ W,     const float* __restrict__ qv,
    const float* __restrict__ kv,    const float* __restrict__ gamma,
    const float* __restrict__ beta,  float* __restrict__ ws, int l)
{
    __shared__ float scale[FD], shift[FD];
    __shared__ __attribute__((aligned(16))) float xs[4][FD];
    __shared__ float redp[4][256];
    __shared__ float red[32];
    int bid = blockIdx.x, t = threadIdx.x;
    int lp = l - 1;
    if (t < 128) {
        float s0 = 0.f, s1 = 0.f;
#pragma unroll
        for (int sl = 0; sl < 8; sl++) {
            s0 += ws[OFF_SUMS + lp*2048 + sl*256 + t];
            s1 += ws[OFF_SUMS + lp*2048 + sl*256 + 128 + t];
        }
        float mu  = s0 * (1.f/2048.f);
        float var = s1 * (1.f/2048.f) - mu*mu;
        float rs  = rsqrtf(var + 1e-5f);
        float gm  = gamma[lp*FD + t], bt = beta[lp*FD + t];
        scale[t] = gm * rs;
        shift[t] = bt - mu * gm * rs;
    }
    __syncthreads();
    int n0 = swizzle_n0(bid);
    {
        int row = t >> 7, f = t & 127;
        size_t e = (size_t)(n0 + row)*FD + f;
        float xv = ws[OFF_X + e] + ws[OFF_M2 + e]*scale[f] + shift[f];
        xs[row][f] = xv;
        ws[OFF_X + e] = xv;
    }
    __syncthreads();
    proj_qsks4(W, qv, kv, ws, l, n0, t, xs, redp, red);
}

// ---------------- k_attn: dense attention + m1 + m2 GEMM + BN partials
// 512 blocks x 512 threads, 4 dst/block -> 2 blocks/CU (16 waves/CU).
// Measured-best structure (R10, 153.6us): 8 barriers, 3-deep pipelines,
// first 2 proj groups + epilogue operands issued at kernel entry.
__global__ __launch_bounds__(512, 4) void k_attn(
    const float* __restrict__ convb, const float* __restrict__ linb,
    float* __restrict__ ws, int l)
{
    __shared__ __attribute__((aligned(16))) float att[4*512];    // 8K
    __shared__ __attribute__((aligned(16))) float redB[8*4*128]; // 16K
    __shared__ __attribute__((aligned(16))) float cat[4*256];    // 4K
    __shared__ float sml[4][2], sls[4][2];
    __shared__ float r1[FD], r2[FD];

    int bid = blockIdx.x, t = threadIdx.x;
    int dstbase = swizzle_n0(bid);
    int g = dstbase >> 9, dloc0 = dstbase & 511;
    int Gd = (dloc0 >= 256) ? 1 : 0;

    // --- early issue: phase-B first 2 proj groups + epilogue operands.
    // These loads complete under the stats/normalize phases (~double the
    // L2 latency), removing the cold-start stall after the barrier.
    int f4 = t & 31, sq = t >> 5;
    int ts = (sq < 8) ? Gd : 1 - Gd;
    const float* P = ws + OFF_PROJ + (size_t)(g*512)*256 + ts*128 + f4*4;
    int s0 = sq * 32;
    float4 buf0[4], buf1[4], buf2[4];
#pragma unroll
    for (int u = 0; u < 4; u++) buf0[u] = *(const float4*)&P[(size_t)(s0+u)*256];
#pragma unroll
    for (int u = 0; u < 4; u++) buf1[u] = *(const float4*)&P[(size_t)(s0+4+u)*256];
    float xpre = ws[OFF_X + (size_t)(dstbase + (t >> 7))*FD + (t & 127)];
    float cb   = convb[l*FD + (t & 127)];
    float lb   = linb[l*FD + (t & 127)];

    // stats: 8 waves, 2 per dst row (half src-range each), merged via LDS
    {
        int w = t >> 6, p = t & 63;
        int d = w >> 1, h = w & 1;
        int dloc = dloc0 + d;
        float q0 = ws[OFF_QS + dstbase + d];
        float q1 = ws[OFF_QS + NN + dstbase + d];
        float sc[4];
#pragma unroll
        for (int j = 0; j < 4; j++) {
            int s = h*256 + p + j*64;
            int tss = (s < 256) ? Gd : 1 - Gd;
            float a = (tss ? q1 : q0) + ws[OFF_KS + tss*NN + g*512 + s];
            a = a > 0.f ? a : 0.2f*a;
            sc[j] = (s == dloc) ? -1e30f : a;
        }
        float lm = fmaxf(fmaxf(sc[0], sc[1]), fmaxf(sc[2], sc[3]));
        for (int off = 32; off; off >>= 1) lm = fmaxf(lm, __shfl_xor(lm, off, 64));
        float ex[4], lsum = 0.f;
#pragma unroll
        for (int j = 0; j < 4; j++) { ex[j] = __expf(sc[j] - lm); lsum += ex[j]; }
        for (int off = 32; off; off >>= 1) lsum += __shfl_xor(lsum, off, 64);
#pragma unroll
        for (int j = 0; j < 4; j++) att[d*512 + h*256 + p + j*64] = ex[j];
        if (p == 0) { sml[d][h] = lm; sls[d][h] = lsum; }
    }
    __syncthreads();
    // normalize across the two halves (exact up to rounding) + zero r1/r2
    {
        int d = t >> 7, s4 = (t & 127) * 4;
        int h = (s4 >= 256) ? 1 : 0;
        float m0 = sml[d][0], m1 = sml[d][1];
        float M = fmaxf(m0, m1);
        float denom = sls[d][0]*__expf(m0 - M) + sls[d][1]*__expf(m1 - M) + 1e-16f;
        float fac = __expf(sml[d][h] - M) / denom;
        float4 a4 = *(float4*)&att[d*512 + s4];
        a4.x *= fac; a4.y *= fac; a4.z *= fac; a4.w *= fac;
        *(float4*)&att[d*512 + s4] = a4;
        if (t < 128) r1[t] = 0.f;
        else if (t < 256) r2[t - 128] = 0.f;
    }
    __syncthreads();

    // phase B: thread = (f4 -> 4 f's, sq -> 32-src chunk); 3-deep pipeline
    // (2 groups in flight ~256cy lead > ~225cy L2 latency).
    float acc[4][4];
#pragma unroll
    for (int d2 = 0; d2 < 4; d2++)
#pragma unroll
        for (int j = 0; j < 4; j++) acc[d2][j] = 0.f;
    {
#pragma unroll
        for (int ii = 0; ii < 8; ii++) {
            const float4* cur = (ii % 3 == 0) ? buf0 : (ii % 3 == 1) ? buf1 : buf2;
            float4* nxt = ((ii+2) % 3 == 0) ? buf0 : ((ii+2) % 3 == 1) ? buf1 : buf2;
            if (ii < 6) {
#pragma unroll
                for (int u = 0; u < 4; u++)
                    nxt[u] = *(const float4*)&P[(size_t)(s0 + (ii+2)*4 + u)*256];
            }
#pragma unroll
            for (int u = 0; u < 4; u++) {
                int s = s0 + ii*4 + u;
                float4 p4 = cur[u];
#pragma unroll
                for (int d2 = 0; d2 < 4; d2++) {
                    float b = att[d2*512 + s];
                    acc[d2][0] += b*p4.x; acc[d2][1] += b*p4.y;
                    acc[d2][2] += b*p4.z; acc[d2][3] += b*p4.w;
                }
            }
        }
    }
    // staged reduction 16 -> 8 partial chunks
    if (sq >= 8) {
#pragma unroll
        for (int d2 = 0; d2 < 4; d2++)
            *(float4*)&redB[((sq - 8)*4 + d2)*128 + f4*4] =
                make_float4(acc[d2][0], acc[d2][1], acc[d2][2], acc[d2][3]);
    }
    __syncthreads();
    if (sq < 8) {
#pragma unroll
        for (int d2 = 0; d2 < 4; d2++) {
            float4 p4 = *(const float4*)&redB[(sq*4 + d2)*128 + f4*4];
            *(float4*)&redB[(sq*4 + d2)*128 + f4*4] =
                make_float4(acc[d2][0]+p4.x, acc[d2][1]+p4.y, acc[d2][2]+p4.z, acc[d2][3]+p4.w);
        }
    }
    __syncthreads();

    // agg reduce (1 output/thread); m1 = relu(agg + conv_b); cat = [x | m1]
    {
        int d2 = t >> 7, f = t & 127;
        float agg = 0.f;
#pragma unroll
        for (int cc = 0; cc < 8; cc++) agg += redB[(cc*4 + d2)*128 + f];
        float m1v = fmaxf(agg + cb, 0.f);
        cat[d2*256 + FD + f] = m1v;
        cat[d2*256 + f] = xpre;
    }
    __syncthreads();

    // m2 GEMM: thread = (f4 -> 4 o's, sq -> 16-c chunk), 3-deep pipeline
#pragma unroll
    for (int d2 = 0; d2 < 4; d2++)
#pragma unroll
        for (int j = 0; j < 4; j++) acc[d2][j] = 0.f;
    {
        const float* lwt = ws + OFF_LWT + l*32768 + f4*4;
        int c0 = sq * 16;
#pragma unroll
        for (int u = 0; u < 4; u++) buf0[u] = *(const float4*)&lwt[(c0+u)*128];
#pragma unroll
        for (int u = 0; u < 4; u++) buf1[u] = *(const float4*)&lwt[(c0+4+u)*128];
#pragma unroll
        for (int ii = 0; ii < 4; ii++) {
            const float4* cur = (ii % 3 == 0) ? buf0 : (ii % 3 == 1) ? buf1 : buf2;
            float4* nxt = ((ii+2) % 3 == 0) ? buf0 : ((ii+2) % 3 == 1) ? buf1 : buf2;
            if (ii < 2) {
#pragma unroll
                for (int u = 0; u < 4; u++)
                    nxt[u] = *(const float4*)&lwt[(c0 + (ii+2)*4 + u)*128];
            }
#pragma unroll
            for (int u = 0; u < 4; u++) {
                int c = c0 + ii*4 + u;
                float4 w4 = cur[u];
#pragma unroll
                for (int d2 = 0; d2 < 4; d2++) {
                    float cv = cat[d2*256 + c];
                    acc[d2][0] += cv*w4.x; acc[d2][1] += cv*w4.y;
                    acc[d2][2] += cv*w4.z; acc[d2][3] += cv*w4.w;
                }
            }
        }
    }
    if (sq >= 8) {
#pragma unroll
        for (int d2 = 0; d2 < 4; d2++)
            *(float4*)&redB[((sq - 8)*4 + d2)*128 + f4*4] =
                make_float4(acc[d2][0], acc[d2][1], acc[d2][2], acc[d2][3]);
    }
    __syncthreads();
    if (sq < 8) {
#pragma unroll
        for (int d2 = 0; d2 < 4; d2++) {
            float4 p4 = *(const float4*)&redB[(sq*4 + d2)*128 + f4*4];
            *(float4*)&redB[(sq*4 + d2)*128 + f4*4] =
                make_float4(acc[d2][0]+p4.x, acc[d2][1]+p4.y, acc[d2][2]+p4.z, acc[d2][3]+p4.w);
        }
    }
    __syncthreads();

    // finalize m2 (1 output/thread), BN partials LDS -> global slots
    {
        int d2 = t >> 7, o = t & 127;
        float m2v = lb;
#pragma unroll
        for (int cc = 0; cc < 8; cc++) m2v += redB[(cc*4 + d2)*128 + o];
        ws[OFF_M2 + (size_t)(dstbase + d2)*FD + o] = m2v;
        atomicAdd(&r1[o], m2v);
        atomicAdd(&r2[o], m2v*m2v);
    }
    __syncthreads();
    if (t < 128) {
        int slot = bid & 7;   // XCD id -> atomics stay XCD-local
        atomicAdd(&ws[OFF_SUMS + l*2048 + slot*256 + t],       r1[t]);
        atomicAdd(&ws[OFF_SUMS + l*2048 + slot*256 + 128 + t], r2[t]);
    }
}

// ---------------- k_bnout: final BN + residual + output transpose
__global__ __launch_bounds__(256) void k_bnout(
    const float* __restrict__ gamma, const float* __restrict__ beta,
    float* __restrict__ ws, float* __restrict__ out)
{
    __shared__ float scale[FD], shift[FD];
    int bid = blockIdx.x, t = threadIdx.x;
    if (t < 128) {
        float s0 = 0.f, s1 = 0.f;
#pragma unroll
        for (int sl = 0; sl < 8; sl++) {
            s0 += ws[OFF_SUMS + 2*2048 + sl*256 + t];
            s1 += ws[OFF_SUMS + 2*2048 + sl*256 + 128 + t];
        }
        float mu  = s0 * (1.f/2048.f);
        float var = s1 * (1.f/2048.f) - mu*mu;
        float rs  = rsqrtf(var + 1e-5f);
        float gm  = gamma[2*FD + t], bt = beta[2*FD + t];
        scale[t] = gm * rs;
        shift[t] = bt - mu * gm * rs;
    }
    __syncthreads();
#pragma unroll
    for (int i = 0; i < 2; i++) {
        int idx = bid*512 + i*256 + t;
        int f = idx & 127, n = idx >> 7;
        float v = ws[OFF_X + idx] + ws[OFF_M2 + idx]*scale[f] + shift[f];
        int gg = n >> 9, ii = n & 511;
        int off = (ii < 256) ? (gg*32768 + f*256 + ii)
                             : (131072 + gg*32768 + f*256 + (ii - 256));
        out[off] = v;
    }
}

extern "C" void kernel_launch(void* const* d_in, const int* in_sizes, int n_in,
                              void* d_out, int out_size, void* d_ws, size_t ws_size,
                              hipStream_t stream) {
    (void)in_sizes; (void)n_in; (void)out_size; (void)ws_size;
    const float* desc0 = (const float*)d_in[0];
    const float* desc1 = (const float*)d_in[1];
    const float* W     = (const float*)d_in[2];
    const float* q     = (const float*)d_in[3];
    const float* kk    = (const float*)d_in[4];
    const float* convb = (const float*)d_in[5];
    const float* linW  = (const float*)d_in[6];
    const float* linb  = (const float*)d_in[7];
    const float* gamma = (const float*)d_in[8];
    const float* beta  = (const float*)d_in[9];
    float* ws  = (float*)d_ws;
    float* out = (float*)d_out;

    hipLaunchKernelGGL(k_pre,  dim3(537), dim3(512), 0, stream, desc0, desc1, W, q, kk, linW, ws);
    hipLaunchKernelGGL(k_attn, dim3(512), dim3(512), 0, stream, convb, linb, ws, 0);
    hipLaunchKernelGGL(k_bp,   dim3(512), dim3(512), 0, stream, W, q, kk, gamma, beta, ws, 1);
    hipLaunchKernelGGL(k_attn, dim3(512), dim3(512), 0, stream, convb, linb, ws, 1);
    hipLaunchKernelGGL(k_bp,   dim3(512), dim3(512), 0, stream, W, q, kk, gamma, beta, ws, 2);
    hipLaunchKernelGGL(k_attn, dim3(512), dim3(512), 0, stream, convb, linb, ws, 2);
    hipLaunchKernelGGL(k_bnout, dim3(512), dim3(256), 0, stream, gamma, beta, ws, out);
}